// Round 12
// baseline (109.312 us; speedup 1.0000x reference)
//
#include <hip/hip_runtime.h>
#include <hip/hip_bf16.h>
#include <cstdint>
#include <cstddef>

#define N_NODES 8192
#define IN_DIM  128
#define OUT_DIM 64
#define LRELU_ALPHA 0.2f
#define S_SLICES 4
#define LOG2E 1.44269504f

using f32x16 = __attribute__((ext_vector_type(16))) float;
using bf16x8 = __attribute__((ext_vector_type(8))) short;
typedef unsigned long long u64;

static __device__ __forceinline__ unsigned short f2bf(float x) {
    union { float f; unsigned u; } v; v.f = x;
    unsigned r = v.u + 0x7FFFu + ((v.u >> 16) & 1u);  // RNE (prep only)
    return (unsigned short)(r >> 16);
}

// pi(j): position of linear node j in the compressed/permuted j-axis.
// bits word W covers j = (W>>2)*256 + 4l + (W&3) at bit l.
static __device__ __forceinline__ int PI(int j) {
    return (((j >> 8) << 2) + (j & 3)) * 64 + ((j & 255) >> 2);
}

// ---------------------------------------------------------------------------
// K1: h = x@W ; svec = (h@a_src)*log2e ; dvecPI = (h@a_dst)*log2e at PI(i) ;
// hpackPI = bf16(h) in MFMA-B layout at PI-slots. Grid 1024 x 256thr.
// ---------------------------------------------------------------------------
__global__ __launch_bounds__(256) void gat_prep(
    const float* __restrict__ x, const float* __restrict__ W,
    const float* __restrict__ a,
    float* __restrict__ svec, float* __restrict__ dvecp,
    unsigned short* __restrict__ hpackp)
{
    __shared__ float shA[4][8][64];
    const int tid = threadIdx.x;
    const int w   = tid >> 6;
    const int f   = tid & 63;
    const int i0  = blockIdx.x * 8;

    float acc[8];
#pragma unroll
    for (int r = 0; r < 8; ++r) acc[r] = 0.f;

    const int k0 = w * 32;
#pragma unroll 2
    for (int k = k0; k < k0 + 32; k += 4) {
        const float w0 = W[(k + 0) * OUT_DIM + f];
        const float w1 = W[(k + 1) * OUT_DIM + f];
        const float w2 = W[(k + 2) * OUT_DIM + f];
        const float w3 = W[(k + 3) * OUT_DIM + f];
#pragma unroll
        for (int r = 0; r < 8; ++r) {
            const float4 xv = *reinterpret_cast<const float4*>(
                x + (size_t)(i0 + r) * IN_DIM + k);
            acc[r] = fmaf(xv.x, w0, acc[r]);
            acc[r] = fmaf(xv.y, w1, acc[r]);
            acc[r] = fmaf(xv.z, w2, acc[r]);
            acc[r] = fmaf(xv.w, w3, acc[r]);
        }
    }
#pragma unroll
    for (int r = 0; r < 8; ++r) shA[w][r][f] = acc[r];
    __syncthreads();

    if (w == 0) {
        // h rows -> bf16 B-fragment slots at permuted positions (8 ushort stores)
        const int fb = f >> 5;
#pragma unroll
        for (int r = 0; r < 8; ++r) {
            const float hv = shA[0][r][f] + shA[1][r][f] + shA[2][r][f] + shA[3][r][f];
            const int P  = PI(i0 + r);
            const int jb = P >> 4;
            const int jh = (P >> 3) & 1;
            const int ep = P & 7;
            hpackp[((size_t)(jb * 2 + fb) * 64 + (f & 31) + 32 * jh) * 8 + ep] = f2bf(hv);
        }
    } else if (w == 1) {
        const float asrc = a[f];
#pragma unroll
        for (int r = 0; r < 8; ++r) {
            const float hv = shA[0][r][f] + shA[1][r][f] + shA[2][r][f] + shA[3][r][f];
            float sv = hv * asrc;
#pragma unroll
            for (int off = 32; off >= 1; off >>= 1) sv += __shfl_xor(sv, off);
            if (f == 0) svec[i0 + r] = sv * LOG2E;
        }
    } else if (w == 2) {
        const float adst = a[OUT_DIM + f];
#pragma unroll
        for (int r = 0; r < 8; ++r) {
            const float hv = shA[0][r][f] + shA[1][r][f] + shA[2][r][f] + shA[3][r][f];
            float dv = hv * adst;
#pragma unroll
            for (int off = 32; off >= 1; off >>= 1) dv += __shfl_xor(dv, off);
            if (f == 0) dvecp[PI(i0 + r)] = dv * LOG2E;
        }
    }
}

// ---------------------------------------------------------------------------
// K2a: adj -> bit matrix, FLAT fill-kernel read pattern (the diagnostic).
// Grid 2048 x 256 (32 waves/CU). Each wave owns 32 consecutive 256-int
// segments (32 KB contiguous); per segment: 1 int4/lane (1 KB/wave/inst),
// 4 ballots -> 4 u64 words, stored TRANSPOSED: bits_t[word_in_row][node].
// Word (seg&31)*4+k holds bit l = adj[row][ (seg&31)*256 + 4l + k ].
// 2-deep prefetch; no barriers, no LDS, no manual waits.
// ---------------------------------------------------------------------------
__global__ __launch_bounds__(256) void gat_compress(
    const int* __restrict__ adj, u64* __restrict__ bits_t)
{
    const int wid  = (blockIdx.x * 256 + threadIdx.x) >> 6;   // 0..8191
    const int l    = threadIdx.x & 63;
    const int seg0 = wid * 32;

    int4 cur = *reinterpret_cast<const int4*>(adj + (size_t)seg0 * 256 + 4 * l);
#pragma unroll 1
    for (int t = 0; t < 32; ++t) {
        const int seg = seg0 + t;
        int4 nxt = cur;
        if (t + 1 < 32)
            nxt = *reinterpret_cast<const int4*>(adj + (size_t)(seg + 1) * 256 + 4 * l);
        const u64 b0 = __ballot(cur.x != 0);
        const u64 b1 = __ballot(cur.y != 0);
        const u64 b2 = __ballot(cur.z != 0);
        const u64 b3 = __ballot(cur.w != 0);
        if (l < 4) {
            const u64 b = (l == 0) ? b0 : (l == 1) ? b1 : (l == 2) ? b2 : b3;
            bits_t[(size_t)((seg & 31) * 4 + l) * N_NODES + (seg >> 5)] = b;
        }
        cur = nxt;
    }
}

// ---------------------------------------------------------------------------
// K2b: compute pass in PI-space (no adj traffic). Grid (256 rb, 4 sl) x
// 256thr, 4 waves. Wave w owns PI-window w*512 within the slice: 8 chunks of
// 64 PI-positions. Per chunk: wv = bits_t[word][i0+row] (per-lane direct,
// 256B coalesced), plains from dvecPI/hpackPI (L2-hot), exp2+mask+pack,
// 8 MFMA. No barriers/ballots/manual-vmcnt in the loop. 2-deep prefetch.
// ---------------------------------------------------------------------------
__global__ __launch_bounds__(256, 2) void gat_main(
    const u64* __restrict__ bits_t,
    const float* __restrict__ svec, const float* __restrict__ dvecp,
    const unsigned short* __restrict__ hpackp,
    float* __restrict__ pO, float* __restrict__ pDen)
{
    __shared__ struct { float red[4][32][64]; float redden[4][32]; } shr;

    const int tid = threadIdx.x;
    const int w   = tid >> 6;
    const int l   = tid & 63;
    const int rb  = blockIdx.x;
    const int sl  = blockIdx.y;
    const int row = l & 31;      // A-fragment row
    const int kh  = l >> 5;      // k-half
    const int i0  = rb * 32;
    const int jwv = sl * 2048 + w * 512;   // wave's PI-window
    const int wd0 = jwv >> 6;              // first word index (0..127)

    const float s_i = svec[i0 + row];      // already * log2e
    const bf16x8* hp = reinterpret_cast<const bf16x8*>(hpackp);

    struct Plains { bf16x8 b[2][4]; float4 d[2][4]; };

    auto loadW = [&](int c) -> u64 {
        return bits_t[(size_t)(wd0 + c) * N_NODES + i0 + row];
    };

    auto loadPlains = [&](int c, Plains& P) {
        const int j0c = jwv + c * 64;
#pragma unroll
        for (int ti = 0; ti < 2; ++ti) {
            const int jg = j0c + ti * 32;
            const int jb = jg >> 4;
#pragma unroll
            for (int q = 0; q < 4; ++q) P.b[ti][q] = hp[(jb * 2 + q) * 64 + l];
            const int j0 = jg + kh * 8;
            P.d[ti][0] = *reinterpret_cast<const float4*>(dvecp + j0);
            P.d[ti][1] = *reinterpret_cast<const float4*>(dvecp + j0 + 4);
            P.d[ti][2] = *reinterpret_cast<const float4*>(dvecp + j0 + 16);
            P.d[ti][3] = *reinterpret_cast<const float4*>(dvecp + j0 + 20);
        }
    };

    f32x16 acc0, acc1;
#pragma unroll
    for (int r = 0; r < 16; ++r) { acc0[r] = 0.f; acc1[r] = 0.f; }
    float den = 0.f;

    auto consume = [&](u64 wv, const Plains& P) {
        const unsigned lo32 = (unsigned)wv;
        const unsigned hi32 = (unsigned)(wv >> 32);
#pragma unroll
        for (int ti = 0; ti < 2; ++ti) {
            const unsigned b32 = ti ? hi32 : lo32;
            const unsigned mq0 = b32 >> (kh * 8);          // PI = jg + kh*8 + e
            const unsigned mq1 = b32 >> (16 + kh * 8);     // PI = jg + 16 + kh*8 + e
            const float dd0[8] = {P.d[ti][0].x, P.d[ti][0].y, P.d[ti][0].z, P.d[ti][0].w,
                                  P.d[ti][1].x, P.d[ti][1].y, P.d[ti][1].z, P.d[ti][1].w};
            const float dd1[8] = {P.d[ti][2].x, P.d[ti][2].y, P.d[ti][2].z, P.d[ti][2].w,
                                  P.d[ti][3].x, P.d[ti][3].y, P.d[ti][3].z, P.d[ti][3].w};
            bf16x8 af0, af1;
#pragma unroll
            for (int e = 0; e < 8; ++e) {
                float ev = s_i + dd0[e];
                ev = fmaxf(ev, LRELU_ALPHA * ev);
                float pv = __builtin_amdgcn_exp2f(ev);
                pv = ((mq0 >> e) & 1u) ? pv : 0.f;
                union { float f; unsigned u; } pu; pu.f = pv;
                pu.u &= 0xFFFF0000u;
                den += pu.f;                 // denominator consistent w/ numerator
                af0[e] = (short)(pu.u >> 16);
            }
#pragma unroll
            for (int e = 0; e < 8; ++e) {
                float ev = s_i + dd1[e];
                ev = fmaxf(ev, LRELU_ALPHA * ev);
                float pv = __builtin_amdgcn_exp2f(ev);
                pv = ((mq1 >> e) & 1u) ? pv : 0.f;
                union { float f; unsigned u; } pu; pu.f = pv;
                pu.u &= 0xFFFF0000u;
                den += pu.f;
                af1[e] = (short)(pu.u >> 16);
            }
            acc0 = __builtin_amdgcn_mfma_f32_32x32x16_bf16(af0, P.b[ti][0], acc0, 0, 0, 0);
            acc1 = __builtin_amdgcn_mfma_f32_32x32x16_bf16(af0, P.b[ti][1], acc1, 0, 0, 0);
            acc0 = __builtin_amdgcn_mfma_f32_32x32x16_bf16(af1, P.b[ti][2], acc0, 0, 0, 0);
            acc1 = __builtin_amdgcn_mfma_f32_32x32x16_bf16(af1, P.b[ti][3], acc1, 0, 0, 0);
        }
    };

    Plains P, Q;
    u64 wvA = loadW(0);
    loadPlains(0, P);

#pragma unroll 1
    for (int c = 0; c < 8; ++c) {
        u64 wvB = 0;
        if (c + 1 < 8) {
            wvB = loadW(c + 1);
            loadPlains(c + 1, Q);
        }
        consume(wvA, P);
        wvA = wvB;
        P = Q;
    }

    // ---- epilogue: verified C/D layout scatter + 4-wave reduce ----
    __syncthreads();
#pragma unroll
    for (int r = 0; r < 16; ++r) {
        const int orow = (r & 3) + 8 * (r >> 2) + 4 * kh;
        shr.red[w][orow][row]      = acc0[r];
        shr.red[w][orow][32 + row] = acc1[r];
    }
    const float dtot = den + __shfl_xor(den, 32);   // combine kh halves
    if (l < 32) shr.redden[w][l] = dtot;
    __syncthreads();

    float* po = pO + ((size_t)rb * S_SLICES + sl) * 2048;
    const float* rf = &shr.red[0][0][0];
    for (int e = tid; e < 2048; e += 256)
        po[e] = rf[e] + rf[2048 + e] + rf[4096 + e] + rf[6144 + e];
    if (tid < 32) {
        pDen[((size_t)rb * S_SLICES + sl) * 32 + tid] =
            shr.redden[0][tid] + shr.redden[1][tid] +
            shr.redden[2][tid] + shr.redden[3][tid];
    }
}

// ---------------------------------------------------------------------------
// K3: sum 4 slice partials, normalize, ELU, write fp32 output. (verified)
// ---------------------------------------------------------------------------
__global__ __launch_bounds__(256) void gat_final(
    const float* __restrict__ pO, const float* __restrict__ pDen,
    float* __restrict__ out)
{
    const int idx = blockIdx.x * 256 + threadIdx.x;
    const int i = idx >> 6;
    const int f = idx & 63;
    const int rb = i >> 5;
    const int r  = i & 31;
    const float* po = pO + (size_t)rb * S_SLICES * 2048 + r * 64 + f;
    const float v = po[0] + po[2048] + po[4096] + po[6144];
    const float* pd = pDen + (size_t)rb * S_SLICES * 32 + r;
    const float dsum = pd[0] + pd[32] + pd[64] + pd[96];
    const float o = v / dsum;
    out[idx] = (o > 0.f) ? o : expm1f(o);   // jax.nn.elu, alpha=1
}

extern "C" void kernel_launch(void* const* d_in, const int* in_sizes, int n_in,
                              void* d_out, int out_size, void* d_ws, size_t ws_size,
                              hipStream_t stream)
{
    const float* x   = (const float*)d_in[0];
    const int*   adj = (const int*)d_in[1];
    const float* W   = (const float*)d_in[2];
    const float* a   = (const float*)d_in[3];
    float* out = (float*)d_out;

    float* svec = (float*)d_ws;                                   // 8192 f32
    float* dvecp = svec + N_NODES;                                // 8192 f32
    unsigned short* hpackp = (unsigned short*)(dvecp + N_NODES);  // 1 MB bf16
    u64* bits_t = (u64*)(hpackp + (size_t)N_NODES * OUT_DIM);     // 8 MB
    float* pO = (float*)(bits_t + (size_t)128 * N_NODES);         // 8 MB
    float* pDen = pO + (size_t)256 * S_SLICES * 2048;             // 128 KB

    gat_prep<<<N_NODES / 8, 256, 0, stream>>>(x, W, a, svec, dvecp, hpackp);
    gat_compress<<<2048, 256, 0, stream>>>(adj, bits_t);
    gat_main<<<dim3(256, S_SLICES), 256, 0, stream>>>(bits_t, svec, dvecp,
                                                      hpackp, pO, pDen);
    gat_final<<<(N_NODES * OUT_DIM) / 256, 256, 0, stream>>>(pO, pDen, out);
}

// Round 13
// 83.430 us; speedup vs baseline: 1.3102x; 1.3102x over previous
//
#include <hip/hip_runtime.h>
#include <hip/hip_bf16.h>
#include <cstdint>
#include <cstddef>

#define N_NODES 8192
#define IN_DIM  128
#define OUT_DIM 64
#define LRELU_ALPHA 0.2f
#define LOG2E 1.44269504f
#define NG 4                 // granules of 2048 j

using f32x16 = __attribute__((ext_vector_type(16))) float;
using bf16x8 = __attribute__((ext_vector_type(8))) short;
typedef unsigned long long u64;

static __device__ __forceinline__ unsigned short f2bf(float x) {
    union { float f; unsigned u; } v; v.f = x;
    unsigned r = v.u + 0x7FFFu + ((v.u >> 16) & 1u);  // RNE (prep only)
    return (unsigned short)(r >> 16);
}

// ---------------------------------------------------------------------------
// K1: h = x@W ; svec = (h@a_src)*log2e ; dvec = (h@a_dst)*log2e ;
// hpack = bf16(h) in MFMA-B layout. (verified R5 version, unchanged)
// ---------------------------------------------------------------------------
__global__ __launch_bounds__(256) void gat_prep(
    const float* __restrict__ x, const float* __restrict__ W,
    const float* __restrict__ a,
    float* __restrict__ svec, float* __restrict__ dvec,
    unsigned short* __restrict__ hpack)
{
    __shared__ float shA[4][8][64];
    const int tid = threadIdx.x;
    const int w   = tid >> 6;
    const int f   = tid & 63;
    const int i0  = blockIdx.x * 8;

    float acc[8];
#pragma unroll
    for (int r = 0; r < 8; ++r) acc[r] = 0.f;

    const int k0 = w * 32;
#pragma unroll 2
    for (int k = k0; k < k0 + 32; k += 4) {
        const float w0 = W[(k + 0) * OUT_DIM + f];
        const float w1 = W[(k + 1) * OUT_DIM + f];
        const float w2 = W[(k + 2) * OUT_DIM + f];
        const float w3 = W[(k + 3) * OUT_DIM + f];
#pragma unroll
        for (int r = 0; r < 8; ++r) {
            const float4 xv = *reinterpret_cast<const float4*>(
                x + (size_t)(i0 + r) * IN_DIM + k);
            acc[r] = fmaf(xv.x, w0, acc[r]);
            acc[r] = fmaf(xv.y, w1, acc[r]);
            acc[r] = fmaf(xv.z, w2, acc[r]);
            acc[r] = fmaf(xv.w, w3, acc[r]);
        }
    }
#pragma unroll
    for (int r = 0; r < 8; ++r) shA[w][r][f] = acc[r];
    __syncthreads();

    if (w == 0) {
        union { unsigned short us[8]; int4 v; } pk;
#pragma unroll
        for (int r = 0; r < 8; ++r) {
            const float hv = shA[0][r][f] + shA[1][r][f] + shA[2][r][f] + shA[3][r][f];
            pk.us[r] = f2bf(hv);
        }
        const int jb    = i0 >> 4;
        const int jhalf = (i0 >> 3) & 1;
        const int fb    = f >> 5;
        const int lidx  = (f & 31) + 32 * jhalf;
        *reinterpret_cast<int4*>(hpack + ((size_t)(jb * 2 + fb) * 64 + lidx) * 8) = pk.v;
    } else if (w == 1) {
        const float asrc = a[f];
#pragma unroll
        for (int r = 0; r < 8; ++r) {
            const float hv = shA[0][r][f] + shA[1][r][f] + shA[2][r][f] + shA[3][r][f];
            float sv = hv * asrc;
#pragma unroll
            for (int off = 32; off >= 1; off >>= 1) sv += __shfl_xor(sv, off);
            if (f == 0) svec[i0 + r] = sv * LOG2E;
        }
    } else if (w == 2) {
        const float adst = a[OUT_DIM + f];
#pragma unroll
        for (int r = 0; r < 8; ++r) {
            const float hv = shA[0][r][f] + shA[1][r][f] + shA[2][r][f] + shA[3][r][f];
            float dv = hv * adst;
#pragma unroll
            for (int off = 32; off >= 1; off >>= 1) dv += __shfl_xor(dv, off);
            if (f == 0) dvec[i0 + r] = dv * LOG2E;
        }
    }
}

// ---------------------------------------------------------------------------
// K2: wave-specialized compress || compute. Grid 256 x 512thr (8 waves).
// Block owns 32 rows x ALL j (its CONTIGUOUS 1MB adj slab). 4 granules of
// 2048 j, double-buffered bit-planes in LDS (4KB each).
//   waves 0..3 (compress): rows w*8..w*8+7; per row read 2048 stride-1
//     dwords (32 x 256B insts, 8KB contiguous run), 2-row register pipeline,
//     __ballot -> 32 u64 words -> swizzled ds_write (slot = wd ^ (row&15)).
//   waves 4..7 (compute): per granule 8 chunks of 64 j: wv = bits broadcast
//     read, plains from dvec/hpack (L2-hot), exp2+mask+pack, 4 MFMA/chunk.
// Sync: ONE __syncthreads per granule (uniform flow, compiler-managed waits,
// no manual vmcnt anywhere). Epilogue: reduce 4 compute waves, normalize,
// ELU, write out directly (no partial buffers, no 3rd kernel).
// ---------------------------------------------------------------------------
__global__ __launch_bounds__(512, 2) void gat_main(
    const int* __restrict__ adj,
    const float* __restrict__ svec, const float* __restrict__ dvec,
    const unsigned short* __restrict__ hpack,
    float* __restrict__ out)
{
    union SH {
        u64 bits[2][32][32];                                     // 2 x 8KB planes
        struct { float red[4][32][64]; float redden[4][32]; } r; // 33KB
    };
    __shared__ SH sh;

    const int tid = threadIdx.x;
    const int w   = tid >> 6;        // 0..7
    const int l   = tid & 63;
    const int rb  = blockIdx.x;
    const int row = l & 31;          // consume: A-fragment row
    const int kh  = l >> 5;          // consume: k-half
    const int i0  = rb * 32;

    const bf16x8* hp = reinterpret_cast<const bf16x8*>(hpack);
    const float s_i = (w >= 4) ? svec[i0 + row] : 0.f;   // already * log2e

    // ---------------- compress-side helpers (waves 0..3) ----------------
    auto loadRow = [&](int (&av)[32], int r32, int j0) {
        const int* base = adj + (size_t)(i0 + r32) * N_NODES + j0;
#pragma unroll
        for (int q = 0; q < 32; ++q) av[q] = base[q * 64 + l];
    };
    auto packRow = [&](const int (&av)[32], int r32, int buf) {
        unsigned lo = 0, hi = 0;
#pragma unroll
        for (int q = 0; q < 32; ++q) {
            const u64 b = __ballot(av[q] != 0);
            if (l == q) { lo = (unsigned)b; hi = (unsigned)(b >> 32); }
        }
        if (l < 32) sh.bits[buf][r32][l ^ (r32 & 15)] = ((u64)hi << 32) | lo;
    };
    auto compressGranule = [&](int g, int buf) {
        const int j0 = g * 2048;
        int avA[32], avB[32];
        loadRow(avA, w * 8, j0);
#pragma unroll
        for (int r8 = 0; r8 < 8; ++r8) {
            const int r32 = w * 8 + r8;
            if (r8 & 1) {
                if (r8 + 1 < 8) loadRow(avA, r32 + 1, j0);
                packRow(avB, r32, buf);
            } else {
                if (r8 + 1 < 8) loadRow(avB, r32 + 1, j0);
                packRow(avA, r32, buf);
            }
        }
    };

    // ---------------- compute-side state (waves 4..7) ----------------
    f32x16 acc0, acc1;
#pragma unroll
    for (int r = 0; r < 16; ++r) { acc0[r] = 0.f; acc1[r] = 0.f; }
    float den = 0.f;

    auto computeGranule = [&](int g, int buf) {
        const int cw = w - 4;
#pragma unroll
        for (int c = 0; c < 8; ++c) {
            const int wd  = cw * 8 + c;                   // word 0..31
            const u64 wv  = sh.bits[buf][row][wd ^ (row & 15)];
            const int jg0 = g * 2048 + wd * 64;           // chunk's 64-j base
#pragma unroll
            for (int ti = 0; ti < 2; ++ti) {
                const int jg = jg0 + ti * 32;
                const int jb = jg >> 4;
                const bf16x8 b00 = hp[(jb * 2 + 0) * 64 + l];
                const bf16x8 b01 = hp[(jb * 2 + 1) * 64 + l];
                const bf16x8 b10 = hp[(jb * 2 + 2) * 64 + l];
                const bf16x8 b11 = hp[(jb * 2 + 3) * 64 + l];
                const int j0 = jg + kh * 8;
                const float4 dA0 = *reinterpret_cast<const float4*>(dvec + j0);
                const float4 dA1 = *reinterpret_cast<const float4*>(dvec + j0 + 4);
                const float4 dB0 = *reinterpret_cast<const float4*>(dvec + j0 + 16);
                const float4 dB1 = *reinterpret_cast<const float4*>(dvec + j0 + 20);

                const unsigned b32 = ti ? (unsigned)(wv >> 32) : (unsigned)wv;
                const unsigned mq0 = b32 >> (kh * 8);          // j = jg + kh*8 + e
                const unsigned mq1 = b32 >> (16 + kh * 8);     // j = jg + 16 + kh*8 + e

                const float dd0[8] = {dA0.x, dA0.y, dA0.z, dA0.w, dA1.x, dA1.y, dA1.z, dA1.w};
                const float dd1[8] = {dB0.x, dB0.y, dB0.z, dB0.w, dB1.x, dB1.y, dB1.z, dB1.w};

                bf16x8 af0, af1;
#pragma unroll
                for (int e = 0; e < 8; ++e) {
                    float ev = s_i + dd0[e];
                    ev = fmaxf(ev, LRELU_ALPHA * ev);
                    float pv = __builtin_amdgcn_exp2f(ev);
                    pv = ((mq0 >> e) & 1u) ? pv : 0.f;
                    union { float f; unsigned u; } pu; pu.f = pv;
                    pu.u &= 0xFFFF0000u;
                    den += pu.f;               // denominator consistent w/ numerator
                    af0[e] = (short)(pu.u >> 16);
                }
#pragma unroll
                for (int e = 0; e < 8; ++e) {
                    float ev = s_i + dd1[e];
                    ev = fmaxf(ev, LRELU_ALPHA * ev);
                    float pv = __builtin_amdgcn_exp2f(ev);
                    pv = ((mq1 >> e) & 1u) ? pv : 0.f;
                    union { float f; unsigned u; } pu; pu.f = pv;
                    pu.u &= 0xFFFF0000u;
                    den += pu.f;
                    af1[e] = (short)(pu.u >> 16);
                }
                acc0 = __builtin_amdgcn_mfma_f32_32x32x16_bf16(af0, b00, acc0, 0, 0, 0);
                acc1 = __builtin_amdgcn_mfma_f32_32x32x16_bf16(af0, b01, acc1, 0, 0, 0);
                acc0 = __builtin_amdgcn_mfma_f32_32x32x16_bf16(af1, b10, acc0, 0, 0, 0);
                acc1 = __builtin_amdgcn_mfma_f32_32x32x16_bf16(af1, b11, acc1, 0, 0, 0);
            }
        }
    };

    // ---------------- pipeline: compress(g+1) || compute(g) ----------------
    if (w < 4) compressGranule(0, 0);
    __syncthreads();

#pragma unroll 1
    for (int g = 0; g < NG; ++g) {
        if (w < 4) {
            if (g + 1 < NG) compressGranule(g + 1, (g + 1) & 1);
        } else {
            computeGranule(g, g & 1);
        }
        __syncthreads();
    }

    // ---------------- epilogue (union becomes reduction buffer) ------------
    if (w >= 4) {
        const int cw = w - 4;
#pragma unroll
        for (int r = 0; r < 16; ++r) {
            const int orow = (r & 3) + 8 * (r >> 2) + 4 * kh;
            sh.r.red[cw][orow][row]      = acc0[r];
            sh.r.red[cw][orow][32 + row] = acc1[r];
        }
        const float dtot = den + __shfl_xor(den, 32);   // combine kh halves
        if (l < 32) sh.r.redden[cw][l] = dtot;
    }
    __syncthreads();

    for (int e = tid; e < 32 * 64; e += 512) {
        const int orow = e >> 6;
        float v = 0.f, dsum = 0.f;
#pragma unroll
        for (int ww = 0; ww < 4; ++ww) {
            v    += sh.r.red[ww][orow][e & 63];
            dsum += sh.r.redden[ww][orow];
        }
        const float o = v / dsum;
        out[(size_t)(i0 + orow) * OUT_DIM + (e & 63)] = (o > 0.f) ? o : expm1f(o);
    }
}

extern "C" void kernel_launch(void* const* d_in, const int* in_sizes, int n_in,
                              void* d_out, int out_size, void* d_ws, size_t ws_size,
                              hipStream_t stream)
{
    const float* x   = (const float*)d_in[0];
    const int*   adj = (const int*)d_in[1];
    const float* W   = (const float*)d_in[2];
    const float* a   = (const float*)d_in[3];
    float* out = (float*)d_out;

    float* svec = (float*)d_ws;                                  // 8192 f32
    float* dvec = svec + N_NODES;                                // 8192 f32
    unsigned short* hpack = (unsigned short*)(dvec + N_NODES);   // 1 MB bf16

    gat_prep<<<N_NODES / 8, 256, 0, stream>>>(x, W, a, svec, dvec, hpack);
    gat_main<<<256, 512, 0, stream>>>(adj, svec, dvec, hpack, out);
}